// Round 17
// baseline (144.872 us; speedup 1.0000x reference)
//
#include <hip/hip_runtime.h>

#define N_NODES 50000
#define N_EDGES 800000
#define IN_DIM 128
#define OUT_DIM 64
#define NEG_INF (-1e30f)
#define GBLK ((N_NODES + 63) / 64)           // 782
#define BSHIFT 6
#define NBUK ((N_NODES + 63) >> 6)           // 782
#define NBUKP 784
#define EB 1024
#define PREB ((N_EDGES + EB - 1) / EB)       // 782
#define NFRAG (3 * 16 + 8)                   // 56 packed weight fragments
#define STAGE_CAP 2048
#define BUKCAP 2048

typedef unsigned short ushort_t;
typedef __attribute__((ext_vector_type(8))) short short8;
typedef __attribute__((ext_vector_type(4))) float f32x4;
typedef __attribute__((ext_vector_type(2))) _Float16 half2_t;

__device__ __forceinline__ unsigned f2bf(float f) {
    unsigned u = __float_as_uint(f);
    u += 0x7fffu + ((u >> 16) & 1u);         // round-to-nearest-even
    return u >> 16;
}
__device__ __forceinline__ float bf2f(ushort_t h) {
    return __uint_as_float((unsigned)h << 16);
}
__device__ __forceinline__ unsigned rl_u(unsigned v, int i) {
    return __builtin_amdgcn_readlane(v, i);
}
__device__ __forceinline__ unsigned pack_h2(float a, float b) {
    auto h = __builtin_amdgcn_cvt_pkrtz(a, b);
    union { decltype(h) h2; unsigned u; } v; v.h2 = h; return v.u;
}
__device__ __forceinline__ void unpack_h2(unsigned u, float& a, float& b) {
    union { unsigned u; half2_t h; } v; v.u = u;
    a = (float)v.h[0];
    b = (float)v.h[1];
}
__device__ __forceinline__ float dot2u(unsigned w, unsigned p, float acc) {
    union { unsigned u; half2_t h; } wv, pv;
    wv.u = w; pv.u = p;
    return __builtin_amdgcn_fdot2(wv.h, pv.h, acc, false);
}

// ---------------------------------------------------------------------------
// Pack weights into MFMA B-fragment order (bf16).
// ---------------------------------------------------------------------------
__global__ void wpack_kernel(const float* __restrict__ Wt,
                             const float* __restrict__ Wres,
                             ushort_t* __restrict__ Wpack) {
    int idx = blockIdx.x * 256 + threadIdx.x;
    if (idx >= NFRAG * 512) return;
    int f = idx >> 9;
    int within = idx & 511;
    int lane = within >> 3;
    int b = within & 7;
    float val;
    if (f < 48) {
        int mat = f >> 4;
        int ct = (f >> 2) & 3;
        int kc = f & 3;
        int k = kc * 32 + (lane >> 4) * 8 + b;
        int c = ct * 16 + (lane & 15);
        const float* W = (mat < 2) ? (Wt + (size_t)mat * IN_DIM * OUT_DIM) : Wres;
        val = W[(size_t)k * OUT_DIM + c];
    } else {
        int f2 = f - 48;
        int ct = f2 >> 1;
        int kc = f2 & 1;
        int k = kc * 32 + (lane >> 4) * 8 + b;
        int c = ct * 16 + (lane & 15);
        val = Wres[(size_t)(IN_DIM + k) * OUT_DIM + c];
    }
    Wpack[idx] = (ushort_t)f2bf(val);
}

// ---------------------------------------------------------------------------
// MFMA GEMM: 64 rows/block, 16 rows/wave, 3 weight mats; al/ar epilogue.
// wxi = f16-pair packed {wx_k0, wx_k1}; xresh = bf16.
// ---------------------------------------------------------------------------
__global__ __launch_bounds__(256) void gemm_kernel(
        const float* __restrict__ x,
        const ushort_t* __restrict__ Wpack,
        const float* __restrict__ wl,
        const float* __restrict__ wr,
        unsigned* __restrict__ wxi,
        ushort_t* __restrict__ xresh,
        float* __restrict__ al,
        float* __restrict__ ar) {
    int wave = threadIdx.x >> 6;
    int lane = threadIdx.x & 63;
    int lr = lane & 15;
    int lg = lane >> 4;
    int row0 = blockIdx.x * 64 + wave * 16;

    int arow = row0 + lr;
    if (arow >= N_NODES) arow = N_NODES - 1;
    const float* xr = x + (size_t)arow * IN_DIM;
    short8 afrag[4];
#pragma unroll
    for (int kc = 0; kc < 4; ++kc) {
        float4 f0 = *(const float4*)(xr + kc * 32 + lg * 8);
        float4 f1 = *(const float4*)(xr + kc * 32 + lg * 8 + 4);
        short8 a;
        a[0] = (short)f2bf(f0.x); a[1] = (short)f2bf(f0.y);
        a[2] = (short)f2bf(f0.z); a[3] = (short)f2bf(f0.w);
        a[4] = (short)f2bf(f1.x); a[5] = (short)f2bf(f1.y);
        a[6] = (short)f2bf(f1.z); a[7] = (short)f2bf(f1.w);
        afrag[kc] = a;
    }

    f32x4 acc[3][4] = {};
#pragma unroll
    for (int kc = 0; kc < 4; ++kc) {
#pragma unroll
        for (int mat = 0; mat < 3; ++mat) {
#pragma unroll
            for (int ct = 0; ct < 4; ++ct) {
                short8 bfrag = *(const short8*)(
                    Wpack + (size_t)(((mat * 4 + ct) * 4 + kc) << 9) + lane * 8);
                acc[mat][ct] = __builtin_amdgcn_mfma_f32_16x16x32_bf16(
                    afrag[kc], bfrag, acc[mat][ct], 0, 0, 0);
            }
        }
    }

#pragma unroll
    for (int r = 0; r < 4; ++r) {
        int gr = row0 + lg * 4 + r;
        if (gr < N_NODES) {
#pragma unroll
            for (int ct = 0; ct < 4; ++ct) {
                wxi[(size_t)gr * OUT_DIM + ct * 16 + lr] =
                    pack_h2(acc[0][ct][r], acc[1][ct][r]);
                xresh[(size_t)gr * OUT_DIM + ct * 16 + lr] =
                    (ushort_t)f2bf(acc[2][ct][r]);
            }
        }
    }

#pragma unroll
    for (int mat = 0; mat < 2; ++mat) {
#pragma unroll
        for (int s = 0; s < 3; ++s) {
            float wlv[4], wrv[4];
#pragma unroll
            for (int ct = 0; ct < 4; ++ct) {
                wlv[ct] = wl[(size_t)(mat * 3 + s) * OUT_DIM + ct * 16 + lr];
                wrv[ct] = wr[(size_t)(mat * 3 + s) * OUT_DIM + ct * 16 + lr];
            }
#pragma unroll
            for (int r = 0; r < 4; ++r) {
                float pl = 0.f, pr = 0.f;
#pragma unroll
                for (int ct = 0; ct < 4; ++ct) {
                    pl = fmaf(acc[mat][ct][r], wlv[ct], pl);
                    pr = fmaf(acc[mat][ct][r], wrv[ct], pr);
                }
#pragma unroll
                for (int off = 1; off < 16; off <<= 1) {
                    pl += __shfl_xor(pl, off);
                    pr += __shfl_xor(pr, off);
                }
                if (lr == 0) {
                    int gr = row0 + lg * 4 + r;
                    if (gr < N_NODES) {
                        al[(size_t)gr * 6 + mat * 3 + s] = pl;
                        ar[(size_t)gr * 6 + mat * 3 + s] = pr;
                    }
                }
            }
        }
    }
}

// ---------------------------------------------------------------------------
// Pass A: score + per-block bucket counting sort in LDS + coalesced flush.
// 8B record: {c | (r&63)<<16, f16x2{s0,s1}}.
// ---------------------------------------------------------------------------
__global__ __launch_bounds__(256) void score_sort_kernel(
        const int* __restrict__ rows,
        const int* __restrict__ cols,
        const float* __restrict__ atten,
        const float* __restrict__ support,
        const float* __restrict__ al,
        const float* __restrict__ ar,
        uint2* __restrict__ etmp,
        uint2* __restrict__ cl) {
    __shared__ int cnt[1024];
    __shared__ int cur[1024];
    __shared__ int aux[256];
    __shared__ uint2 stage[EB];
    int t = threadIdx.x;
    cnt[t] = 0; cnt[t + 256] = 0; cnt[t + 512] = 0; cnt[t + 768] = 0;
    __syncthreads();
    int base0 = blockIdx.x * EB;
    int nval = min(EB, N_EDGES - base0);

    int r_[4], c_[4];
    float s0_[4], s1_[4];
#pragma unroll
    for (int i = 0; i < 4; ++i) {
        int e = base0 + i * 256 + t;
        bool v = e < N_EDGES;
        int r = v ? rows[e] : -1;
        int c = v ? cols[e] : 0;
        float sc0 = 0.f, sc1 = 0.f;
        if (v) {
            float a0 = atten[e], a1 = atten[N_EDGES + e];
            float sp0 = support[e], sp1 = support[N_EDGES + e];
            const float* A = al + (size_t)r * 6;
            const float* B = ar + (size_t)c * 6;
            sc0 = (A[0] + B[0]) * a0 + (A[1] + B[1]) * a1 + (A[2] + B[2]) * sp0;
            sc1 = (A[3] + B[3]) * a0 + (A[4] + B[4]) * a1 + (A[5] + B[5]) * sp1;
            atomicAdd(&cnt[r >> BSHIFT], 1);
        }
        r_[i] = r; c_[i] = c; s0_[i] = sc0; s1_[i] = sc1;
    }
    __syncthreads();
    // exclusive scan of cnt[0..1023], 4 entries/thread
    int v0 = cnt[4 * t], v1 = cnt[4 * t + 1], v2 = cnt[4 * t + 2], v3 = cnt[4 * t + 3];
    int ps = v0 + v1 + v2 + v3;
    aux[t] = ps;
    __syncthreads();
    int val = ps;
    for (int off = 1; off < 256; off <<= 1) {
        int y = (t >= off) ? aux[t - off] : 0;
        __syncthreads();
        val += y; aux[t] = val;
        __syncthreads();
    }
    int e0x = val - ps;
    cur[4 * t]     = e0x;
    cur[4 * t + 1] = e0x + v0;
    cur[4 * t + 2] = e0x + v0 + v1;
    cur[4 * t + 3] = e0x + v0 + v1 + v2;
    size_t cb = (size_t)blockIdx.x * NBUKP;
    int vv[4] = {v0, v1, v2, v3};
#pragma unroll
    for (int j = 0; j < 4; ++j) {
        int idx = 4 * t + j;
        if (idx < NBUK) cl[cb + idx] = make_uint2((unsigned)vv[j], (unsigned)cur[idx]);
    }
    __syncthreads();
#pragma unroll
    for (int i = 0; i < 4; ++i) {
        if (r_[i] < 0) continue;
        int pos = atomicAdd(&cur[r_[i] >> BSHIFT], 1);
        uint2 pv;
        pv.x = (unsigned)c_[i] | ((unsigned)(r_[i] & 63) << 16);
        pv.y = pack_h2(s0_[i], s1_[i]);
        stage[pos] = pv;
    }
    __syncthreads();
    for (int i = t; i < nval; i += 256)
        etmp[(size_t)base0 + i] = stage[i];
}

// ---------------------------------------------------------------------------
// Pass B: per-bucket run-copy + LDS counting sort by row.
// Bucket k writes edata[k*BUKCAP ...]; rowinfo[row] = {beg(abs), deg}.
// ---------------------------------------------------------------------------
__global__ __launch_bounds__(256) void sortb_kernel(
        const uint2* __restrict__ cl,
        const uint2* __restrict__ etmp,
        uint2* __restrict__ edata,
        uint2* __restrict__ rowinfo) {
    __shared__ uint2 stage[STAGE_CAP];   // 16 KB
    __shared__ int rpos[PREB + 2];
    __shared__ int lloff[PREB];
    __shared__ int aux[256];
    __shared__ int hist[64], rcur[64];
    int k = blockIdx.x, t = threadIdx.x;
    int base = k * BUKCAP;

    // load this bucket's {cnt, loff} across blocks
    for (int b = t; b < PREB; b += 256) {
        uint2 v2 = cl[(size_t)b * NBUKP + k];
        rpos[b] = (int)v2.x;
        lloff[b] = (int)v2.y;
    }
    if (t < 64) hist[t] = 0;
    __syncthreads();
    // exclusive scan of rpos[0..PREB-1] -> run positions; rpos[PREB] = nb
    int v[4];
    int idx4 = 4 * t;
#pragma unroll
    for (int i = 0; i < 4; ++i) v[i] = (idx4 + i < PREB) ? rpos[idx4 + i] : 0;
    __syncthreads();
    int s = 0;
#pragma unroll
    for (int i = 0; i < 4; ++i) { int tmp = v[i]; v[i] = s; s += tmp; }
    aux[t] = s;
    __syncthreads();
    int tv = s;
    for (int off = 1; off < 256; off <<= 1) {
        int y = (t >= off) ? aux[t - off] : 0;
        __syncthreads();
        tv += y; aux[t] = tv;
        __syncthreads();
    }
    int ofs = tv - s;
#pragma unroll
    for (int i = 0; i < 4; ++i)
        if (idx4 + i <= PREB) rpos[idx4 + i] = ofs + v[i];
    __syncthreads();
    int nb = rpos[PREB];

    // run-per-thread copy into stage + row histogram
    for (int b = t; b < PREB; b += 256) {
        int s0 = rpos[b];
        int n = rpos[b + 1] - s0;
        int lo = lloff[b];
        const uint2* src = etmp + (size_t)b * EB + lo;
        for (int i = 0; i < n; ++i) {
            uint2 rec = src[i];
            int j = s0 + i;
            if (j < STAGE_CAP) stage[j] = rec;
            atomicAdd(&hist[(rec.x >> 16) & 63], 1);
        }
    }
    __syncthreads();
    // exclusive scan of hist[64]
    int hv = (t < 64) ? hist[t] : 0;
    aux[t] = hv;
    __syncthreads();
    int hval = hv;
    for (int off = 1; off < 64; off <<= 1) {
        int y = (t >= off && t < 64) ? aux[t - off] : 0;
        __syncthreads();
        hval += y; aux[t] = hval;
        __syncthreads();
    }
    if (t < 64) {
        int start = hval - hv;
        rcur[t] = start;
        int row = (k << BSHIFT) + t;
        if (row < N_NODES)
            rowinfo[row] = make_uint2((unsigned)(base + start), (unsigned)hv);
    }
    __syncthreads();
    // place (scattered writes within this bucket's own region only)
    for (int j = t; j < nb; j += 256) {
        uint2 rec;
        if (j < STAGE_CAP) rec = stage[j];
        else {
            int lo = 0, hi = PREB - 1;
            while (lo < hi) { int mid = (lo + hi + 1) >> 1; if (rpos[mid] <= j) lo = mid; else hi = mid - 1; }
            rec = etmp[(size_t)lo * EB + lloff[lo] + (j - rpos[lo])];
        }
        int rl = (rec.x >> 16) & 63;
        int dst = atomicAdd(&rcur[rl], 1);
        if (dst < BUKCAP) edata[(size_t)base + dst] = rec;
    }
}

// ---------------------------------------------------------------------------
// Merged attention + residual: block b = bucket b = rows [64b, 64b+64).
// Phase 1: wave w computes rows w, w+4, ... -> bf16 results in LDS.
// Phase 2: wave w does the residual MFMA for its 16-row group + elu + out.
// ---------------------------------------------------------------------------
__global__ __launch_bounds__(256) void attn_resid_kernel(
        const uint2* __restrict__ rowinfo,
        const uint2* __restrict__ edata,
        const unsigned* __restrict__ wxi,
        const ushort_t* __restrict__ xresh,
        const ushort_t* __restrict__ Wpack,
        float* __restrict__ out) {
    __shared__ ushort_t aacc_s[64][72];   // +8 pad: MFMA A-frag reads 2-way free
    int t = threadIdx.x;
    int wave = t >> 6;
    int lane = t & 63;
    // zero-init (tail rows feed discarded MFMA outputs, keep them finite)
    for (int i = t; i < 64 * 36; i += 256) ((unsigned*)aacc_s)[i] = 0;
    __syncthreads();

    for (int rr = wave; rr < 64; rr += 4) {
        int row = blockIdx.x * 64 + rr;
        if (row >= N_NODES) continue;
        uint2 ri = rowinfo[row];
        int beg = (int)ri.x;
        int deg = (int)ri.y;
        float a = 0.f;

        if (deg > 0 && deg <= 64) {
            bool valid = lane < deg;
            uint2 ed = edata[valid ? beg + lane : beg];
            unsigned c = ed.x & 0xFFFFu;
            float sc0, sc1;
            unpack_h2(ed.y, sc0, sc1);
            if (!valid) { sc0 = NEG_INF; sc1 = NEG_INF; }
            float m0 = sc0, m1 = sc1;
#pragma unroll
            for (int off = 32; off > 0; off >>= 1) {
                m0 = fmaxf(m0, __shfl_xor(m0, off));
                m1 = fmaxf(m1, __shfl_xor(m1, off));
            }
            float e0 = valid ? __expf(sc0 - m0) : 0.f;
            float e1 = valid ? __expf(sc1 - m1) : 0.f;
            float l0 = e0, l1 = e1;
#pragma unroll
            for (int off = 32; off > 0; off >>= 1) {
                l0 += __shfl_xor(l0, off);
                l1 += __shfl_xor(l1, off);
            }
            unsigned pp = pack_h2(e0 / l0, e1 / l1);
            float acc8[8] = {};
            int i = 0;
            for (; i + 8 <= deg; i += 8) {
                unsigned cc[8], vv8[8];
#pragma unroll
                for (int j = 0; j < 8; ++j) cc[j] = rl_u(c, i + j);
#pragma unroll
                for (int j = 0; j < 8; ++j) vv8[j] = wxi[(size_t)cc[j] * OUT_DIM + lane];
#pragma unroll
                for (int j = 0; j < 8; ++j)
                    acc8[j] = dot2u(vv8[j], rl_u(pp, i + j), acc8[j]);
            }
            for (; i < deg; ++i) {
                unsigned ci = rl_u(c, i);
                unsigned vw = wxi[(size_t)ci * OUT_DIM + lane];
                acc8[0] = dot2u(vw, rl_u(pp, i), acc8[0]);
            }
            a = ((acc8[0] + acc8[1]) + (acc8[2] + acc8[3]))
              + ((acc8[4] + acc8[5]) + (acc8[6] + acc8[7]));
        } else if (deg > 64) {
            int end = beg + deg;
            float m0 = NEG_INF, l0 = 0.f, m1 = NEG_INF, l1 = 0.f;
            for (int base = beg; base < end; base += 64) {
                int pos = base + lane;
                bool valid = pos < end;
                uint2 ed = edata[valid ? pos : beg];
                float sc0, sc1;
                unpack_h2(ed.y, sc0, sc1);
                if (!valid) { sc0 = NEG_INF; sc1 = NEG_INF; }
                float cm0 = sc0, cm1 = sc1;
#pragma unroll
                for (int off = 32; off > 0; off >>= 1) {
                    cm0 = fmaxf(cm0, __shfl_xor(cm0, off));
                    cm1 = fmaxf(cm1, __shfl_xor(cm1, off));
                }
                float mn0 = fmaxf(m0, cm0), mn1 = fmaxf(m1, cm1);
                float e0 = valid ? __expf(sc0 - mn0) : 0.f;
                float e1 = valid ? __expf(sc1 - mn1) : 0.f;
#pragma unroll
                for (int off = 32; off > 0; off >>= 1) {
                    e0 += __shfl_xor(e0, off);
                    e1 += __shfl_xor(e1, off);
                }
                l0 = l0 * __expf(m0 - mn0) + e0;
                l1 = l1 * __expf(m1 - mn1) + e1;
                m0 = mn0; m1 = mn1;
            }
            float inv0 = 1.f / l0, inv1 = 1.f / l1;
            for (int base = beg; base < end; base += 64) {
                int pos = base + lane;
                bool valid = pos < end;
                uint2 ed = edata[valid ? pos : beg];
                unsigned c = ed.x & 0xFFFFu;
                float sc0, sc1;
                unpack_h2(ed.y, sc0, sc1);
                float p0 = valid ? __expf(sc0 - m0) * inv0 : 0.f;
                float p1 = valid ? __expf(sc1 - m1) * inv1 : 0.f;
                unsigned pp = pack_h2(p0, p1);
                int cnt = min(64, end - base);
                for (int i = 0; i < cnt; ++i) {
                    unsigned ci = rl_u(c, i);
                    unsigned vw = wxi[(size_t)ci * OUT_DIM + lane];
                    a = dot2u(vw, rl_u(pp, i), a);
                }
            }
        }
        aacc_s[rr][lane] = (ushort_t)f2bf(a);
    }
    __syncthreads();

    // phase 2: residual MFMA from LDS
    int lr = lane & 15;
    int lg = lane >> 4;
    int row0 = blockIdx.x * 64 + wave * 16;
    int rloc = wave * 16 + lr;
    short8 af[2];
#pragma unroll
    for (int kc = 0; kc < 2; ++kc)
        af[kc] = *(const short8*)&aacc_s[rloc][kc * 32 + lg * 8];
    f32x4 acc4[4] = {};
#pragma unroll
    for (int kc = 0; kc < 2; ++kc) {
#pragma unroll
        for (int ct = 0; ct < 4; ++ct) {
            short8 bfrag = *(const short8*)(
                Wpack + (size_t)((48 + ct * 2 + kc) << 9) + lane * 8);
            acc4[ct] = __builtin_amdgcn_mfma_f32_16x16x32_bf16(
                af[kc], bfrag, acc4[ct], 0, 0, 0);
        }
    }
#pragma unroll
    for (int r = 0; r < 4; ++r) {
        int gr = row0 + lg * 4 + r;
        if (gr < N_NODES) {
#pragma unroll
            for (int ct = 0; ct < 4; ++ct) {
                float v = acc4[ct][r] + bf2f(xresh[(size_t)gr * OUT_DIM + ct * 16 + lr]);
                out[(size_t)gr * OUT_DIM + ct * 16 + lr] = (v > 0.f) ? v : expm1f(v);
            }
        }
    }
}

extern "C" void kernel_launch(void* const* d_in, const int* in_sizes, int n_in,
                              void* d_out, int out_size, void* d_ws, size_t ws_size,
                              hipStream_t stream) {
    const float* x       = (const float*)d_in[0];
    const float* support = (const float*)d_in[1];
    const float* atten   = (const float*)d_in[2];
    const float* Wt      = (const float*)d_in[3];
    const float* wl      = (const float*)d_in[4];
    const float* wr      = (const float*)d_in[5];
    const float* Wres    = (const float*)d_in[6];
    const int*   rows    = (const int*)d_in[7];
    const int*   cols    = (const int*)d_in[8];
    float* out = (float*)d_out;

    // workspace layout (16B-aligned sections)
    unsigned* wxi    = (unsigned*)d_ws;                                // N*64
    ushort_t* xresh  = (ushort_t*)(wxi + (size_t)N_NODES * OUT_DIM);   // N*64 bf16
    float* al        = (float*)(xresh + (size_t)N_NODES * OUT_DIM);    // N*6
    float* ar        = al + (size_t)N_NODES * 6;                       // N*6
    uint2* etmp      = (uint2*)(ar + (size_t)N_NODES * 6);             // E * 8B
    uint2* edata     = etmp + (size_t)N_EDGES;                         // NBUK*BUKCAP * 8B
    uint2* rowinfo   = edata + (size_t)NBUK * BUKCAP;                  // N
    uint2* cl        = rowinfo + N_NODES + 4;                          // PREB*NBUKP
    ushort_t* Wpack  = (ushort_t*)(cl + (size_t)PREB * NBUKP);         // NFRAG*512

    wpack_kernel<<<(NFRAG * 512 + 255) / 256, 256, 0, stream>>>(Wt, Wres, Wpack);
    gemm_kernel<<<GBLK, 256, 0, stream>>>(x, Wpack, wl, wr, wxi, xresh, al, ar);
    score_sort_kernel<<<PREB, 256, 0, stream>>>(
        rows, cols, atten, support, al, ar, etmp, cl);
    sortb_kernel<<<NBUK, 256, 0, stream>>>(cl, etmp, edata, rowinfo);
    attn_resid_kernel<<<NBUK, 256, 0, stream>>>(
        rowinfo, edata, wxi, xresh, Wpack, out);
}

// Round 18
// 123.159 us; speedup vs baseline: 1.1763x; 1.1763x over previous
//
#include <hip/hip_runtime.h>

#define N_NODES 50000
#define N_EDGES 800000
#define IN_DIM 128
#define OUT_DIM 64
#define NEG_INF (-1e30f)
#define GBLK ((N_NODES + 63) / 64)           // 782
#define BSHIFT 6
#define NBUK ((N_NODES + 63) >> 6)           // 782
#define NBUKP 784
#define EB 1024
#define PREB ((N_EDGES + EB - 1) / EB)       // 782
#define NFRAG (3 * 16 + 8)                   // 56 packed weight fragments
#define STAGE_CAP 2048
#define BUKCAP 2048

typedef unsigned short ushort_t;
typedef __attribute__((ext_vector_type(8))) short short8;
typedef __attribute__((ext_vector_type(4))) float f32x4;
typedef __attribute__((ext_vector_type(2))) _Float16 half2_t;

__device__ __forceinline__ unsigned f2bf(float f) {
    unsigned u = __float_as_uint(f);
    u += 0x7fffu + ((u >> 16) & 1u);         // round-to-nearest-even
    return u >> 16;
}
__device__ __forceinline__ float bf2f(ushort_t h) {
    return __uint_as_float((unsigned)h << 16);
}
__device__ __forceinline__ unsigned rl_u(unsigned v, int i) {
    return __builtin_amdgcn_readlane(v, i);
}
__device__ __forceinline__ unsigned pack_h2(float a, float b) {
    auto h = __builtin_amdgcn_cvt_pkrtz(a, b);
    union { decltype(h) h2; unsigned u; } v; v.h2 = h; return v.u;
}
__device__ __forceinline__ void unpack_h2(unsigned u, float& a, float& b) {
    union { unsigned u; half2_t h; } v; v.u = u;
    a = (float)v.h[0];
    b = (float)v.h[1];
}
__device__ __forceinline__ float dot2u(unsigned w, unsigned p, float acc) {
    union { unsigned u; half2_t h; } wv, pv;
    wv.u = w; pv.u = p;
    return __builtin_amdgcn_fdot2(wv.h, pv.h, acc, false);
}

// ---------------------------------------------------------------------------
// Pack weights into MFMA B-fragment order (bf16).
// ---------------------------------------------------------------------------
__global__ void wpack_kernel(const float* __restrict__ Wt,
                             const float* __restrict__ Wres,
                             ushort_t* __restrict__ Wpack) {
    int idx = blockIdx.x * 256 + threadIdx.x;
    if (idx >= NFRAG * 512) return;
    int f = idx >> 9;
    int within = idx & 511;
    int lane = within >> 3;
    int b = within & 7;
    float val;
    if (f < 48) {
        int mat = f >> 4;
        int ct = (f >> 2) & 3;
        int kc = f & 3;
        int k = kc * 32 + (lane >> 4) * 8 + b;
        int c = ct * 16 + (lane & 15);
        const float* W = (mat < 2) ? (Wt + (size_t)mat * IN_DIM * OUT_DIM) : Wres;
        val = W[(size_t)k * OUT_DIM + c];
    } else {
        int f2 = f - 48;
        int ct = f2 >> 1;
        int kc = f2 & 1;
        int k = kc * 32 + (lane >> 4) * 8 + b;
        int c = ct * 16 + (lane & 15);
        val = Wres[(size_t)(IN_DIM + k) * OUT_DIM + c];
    }
    Wpack[idx] = (ushort_t)f2bf(val);
}

// ---------------------------------------------------------------------------
// MFMA GEMM: 64 rows/block, 16 rows/wave, 3 weight mats; al/ar epilogue.
// wxi = f16-pair packed {wx_k0, wx_k1}; xresh = bf16.
// ---------------------------------------------------------------------------
__global__ __launch_bounds__(256) void gemm_kernel(
        const float* __restrict__ x,
        const ushort_t* __restrict__ Wpack,
        const float* __restrict__ wl,
        const float* __restrict__ wr,
        unsigned* __restrict__ wxi,
        ushort_t* __restrict__ xresh,
        float* __restrict__ al,
        float* __restrict__ ar) {
    int wave = threadIdx.x >> 6;
    int lane = threadIdx.x & 63;
    int lr = lane & 15;
    int lg = lane >> 4;
    int row0 = blockIdx.x * 64 + wave * 16;

    int arow = row0 + lr;
    if (arow >= N_NODES) arow = N_NODES - 1;
    const float* xr = x + (size_t)arow * IN_DIM;
    short8 afrag[4];
#pragma unroll
    for (int kc = 0; kc < 4; ++kc) {
        float4 f0 = *(const float4*)(xr + kc * 32 + lg * 8);
        float4 f1 = *(const float4*)(xr + kc * 32 + lg * 8 + 4);
        short8 a;
        a[0] = (short)f2bf(f0.x); a[1] = (short)f2bf(f0.y);
        a[2] = (short)f2bf(f0.z); a[3] = (short)f2bf(f0.w);
        a[4] = (short)f2bf(f1.x); a[5] = (short)f2bf(f1.y);
        a[6] = (short)f2bf(f1.z); a[7] = (short)f2bf(f1.w);
        afrag[kc] = a;
    }

    f32x4 acc[3][4] = {};
#pragma unroll
    for (int kc = 0; kc < 4; ++kc) {
#pragma unroll
        for (int mat = 0; mat < 3; ++mat) {
#pragma unroll
            for (int ct = 0; ct < 4; ++ct) {
                short8 bfrag = *(const short8*)(
                    Wpack + (size_t)(((mat * 4 + ct) * 4 + kc) << 9) + lane * 8);
                acc[mat][ct] = __builtin_amdgcn_mfma_f32_16x16x32_bf16(
                    afrag[kc], bfrag, acc[mat][ct], 0, 0, 0);
            }
        }
    }

#pragma unroll
    for (int r = 0; r < 4; ++r) {
        int gr = row0 + lg * 4 + r;
        if (gr < N_NODES) {
#pragma unroll
            for (int ct = 0; ct < 4; ++ct) {
                wxi[(size_t)gr * OUT_DIM + ct * 16 + lr] =
                    pack_h2(acc[0][ct][r], acc[1][ct][r]);
                xresh[(size_t)gr * OUT_DIM + ct * 16 + lr] =
                    (ushort_t)f2bf(acc[2][ct][r]);
            }
        }
    }

#pragma unroll
    for (int mat = 0; mat < 2; ++mat) {
#pragma unroll
        for (int s = 0; s < 3; ++s) {
            float wlv[4], wrv[4];
#pragma unroll
            for (int ct = 0; ct < 4; ++ct) {
                wlv[ct] = wl[(size_t)(mat * 3 + s) * OUT_DIM + ct * 16 + lr];
                wrv[ct] = wr[(size_t)(mat * 3 + s) * OUT_DIM + ct * 16 + lr];
            }
#pragma unroll
            for (int r = 0; r < 4; ++r) {
                float pl = 0.f, pr = 0.f;
#pragma unroll
                for (int ct = 0; ct < 4; ++ct) {
                    pl = fmaf(acc[mat][ct][r], wlv[ct], pl);
                    pr = fmaf(acc[mat][ct][r], wrv[ct], pr);
                }
#pragma unroll
                for (int off = 1; off < 16; off <<= 1) {
                    pl += __shfl_xor(pl, off);
                    pr += __shfl_xor(pr, off);
                }
                if (lr == 0) {
                    int gr = row0 + lg * 4 + r;
                    if (gr < N_NODES) {
                        al[(size_t)gr * 6 + mat * 3 + s] = pl;
                        ar[(size_t)gr * 6 + mat * 3 + s] = pr;
                    }
                }
            }
        }
    }
}

// ---------------------------------------------------------------------------
// Pass A: score + per-block bucket counting sort in LDS + coalesced flush.
// 8B record: {c | (r&63)<<16, f16x2{s0,s1}}.
// ---------------------------------------------------------------------------
__global__ __launch_bounds__(256) void score_sort_kernel(
        const int* __restrict__ rows,
        const int* __restrict__ cols,
        const float* __restrict__ atten,
        const float* __restrict__ support,
        const float* __restrict__ al,
        const float* __restrict__ ar,
        uint2* __restrict__ etmp,
        uint2* __restrict__ cl) {
    __shared__ int cnt[1024];
    __shared__ int cur[1024];
    __shared__ int aux[256];
    __shared__ uint2 stage[EB];
    int t = threadIdx.x;
    cnt[t] = 0; cnt[t + 256] = 0; cnt[t + 512] = 0; cnt[t + 768] = 0;
    __syncthreads();
    int base0 = blockIdx.x * EB;
    int nval = min(EB, N_EDGES - base0);

    int r_[4], c_[4];
    float s0_[4], s1_[4];
#pragma unroll
    for (int i = 0; i < 4; ++i) {
        int e = base0 + i * 256 + t;
        bool v = e < N_EDGES;
        int r = v ? rows[e] : -1;
        int c = v ? cols[e] : 0;
        float sc0 = 0.f, sc1 = 0.f;
        if (v) {
            float a0 = atten[e], a1 = atten[N_EDGES + e];
            float sp0 = support[e], sp1 = support[N_EDGES + e];
            const float* A = al + (size_t)r * 6;
            const float* B = ar + (size_t)c * 6;
            sc0 = (A[0] + B[0]) * a0 + (A[1] + B[1]) * a1 + (A[2] + B[2]) * sp0;
            sc1 = (A[3] + B[3]) * a0 + (A[4] + B[4]) * a1 + (A[5] + B[5]) * sp1;
            atomicAdd(&cnt[r >> BSHIFT], 1);
        }
        r_[i] = r; c_[i] = c; s0_[i] = sc0; s1_[i] = sc1;
    }
    __syncthreads();
    // exclusive scan of cnt[0..1023], 4 entries/thread
    int v0 = cnt[4 * t], v1 = cnt[4 * t + 1], v2 = cnt[4 * t + 2], v3 = cnt[4 * t + 3];
    int ps = v0 + v1 + v2 + v3;
    aux[t] = ps;
    __syncthreads();
    int val = ps;
    for (int off = 1; off < 256; off <<= 1) {
        int y = (t >= off) ? aux[t - off] : 0;
        __syncthreads();
        val += y; aux[t] = val;
        __syncthreads();
    }
    int e0x = val - ps;
    cur[4 * t]     = e0x;
    cur[4 * t + 1] = e0x + v0;
    cur[4 * t + 2] = e0x + v0 + v1;
    cur[4 * t + 3] = e0x + v0 + v1 + v2;
    size_t cb = (size_t)blockIdx.x * NBUKP;
    int vv[4] = {v0, v1, v2, v3};
#pragma unroll
    for (int j = 0; j < 4; ++j) {
        int idx = 4 * t + j;
        if (idx < NBUK) cl[cb + idx] = make_uint2((unsigned)vv[j], (unsigned)cur[idx]);
    }
    __syncthreads();
#pragma unroll
    for (int i = 0; i < 4; ++i) {
        if (r_[i] < 0) continue;
        int pos = atomicAdd(&cur[r_[i] >> BSHIFT], 1);
        uint2 pv;
        pv.x = (unsigned)c_[i] | ((unsigned)(r_[i] & 63) << 16);
        pv.y = pack_h2(s0_[i], s1_[i]);
        stage[pos] = pv;
    }
    __syncthreads();
    for (int i = t; i < nval; i += 256)
        etmp[(size_t)base0 + i] = stage[i];
}

// ---------------------------------------------------------------------------
// Pass B: per-bucket run-copy + LDS counting sort by row.
// Bucket k writes edata[k*BUKCAP ...]; rowinfo[row] = {beg(abs), deg}.
// ---------------------------------------------------------------------------
__global__ __launch_bounds__(256) void sortb_kernel(
        const uint2* __restrict__ cl,
        const uint2* __restrict__ etmp,
        uint2* __restrict__ edata,
        uint2* __restrict__ rowinfo) {
    __shared__ uint2 stage[STAGE_CAP];   // 16 KB
    __shared__ int rpos[PREB + 2];
    __shared__ int lloff[PREB];
    __shared__ int aux[256];
    __shared__ int hist[64], rcur[64];
    int k = blockIdx.x, t = threadIdx.x;
    int base = k * BUKCAP;

    // load this bucket's {cnt, loff} across blocks
    for (int b = t; b < PREB; b += 256) {
        uint2 v2 = cl[(size_t)b * NBUKP + k];
        rpos[b] = (int)v2.x;
        lloff[b] = (int)v2.y;
    }
    if (t < 64) hist[t] = 0;
    __syncthreads();
    // exclusive scan of rpos[0..PREB-1] -> run positions; rpos[PREB] = nb
    int v[4];
    int idx4 = 4 * t;
#pragma unroll
    for (int i = 0; i < 4; ++i) v[i] = (idx4 + i < PREB) ? rpos[idx4 + i] : 0;
    __syncthreads();
    int s = 0;
#pragma unroll
    for (int i = 0; i < 4; ++i) { int tmp = v[i]; v[i] = s; s += tmp; }
    aux[t] = s;
    __syncthreads();
    int tv = s;
    for (int off = 1; off < 256; off <<= 1) {
        int y = (t >= off) ? aux[t - off] : 0;
        __syncthreads();
        tv += y; aux[t] = tv;
        __syncthreads();
    }
    int ofs = tv - s;
#pragma unroll
    for (int i = 0; i < 4; ++i)
        if (idx4 + i <= PREB) rpos[idx4 + i] = ofs + v[i];
    __syncthreads();
    int nb = rpos[PREB];

    // run-per-thread copy into stage + row histogram
    for (int b = t; b < PREB; b += 256) {
        int s0 = rpos[b];
        int n = rpos[b + 1] - s0;
        int lo = lloff[b];
        const uint2* src = etmp + (size_t)b * EB + lo;
        for (int i = 0; i < n; ++i) {
            uint2 rec = src[i];
            int j = s0 + i;
            if (j < STAGE_CAP) stage[j] = rec;
            atomicAdd(&hist[(rec.x >> 16) & 63], 1);
        }
    }
    __syncthreads();
    // exclusive scan of hist[64]
    int hv = (t < 64) ? hist[t] : 0;
    aux[t] = hv;
    __syncthreads();
    int hval = hv;
    for (int off = 1; off < 64; off <<= 1) {
        int y = (t >= off && t < 64) ? aux[t - off] : 0;
        __syncthreads();
        hval += y; aux[t] = hval;
        __syncthreads();
    }
    if (t < 64) {
        int start = hval - hv;
        rcur[t] = start;
        int row = (k << BSHIFT) + t;
        if (row < N_NODES)
            rowinfo[row] = make_uint2((unsigned)(base + start), (unsigned)hv);
    }
    __syncthreads();
    // place (scattered writes within this bucket's own region only)
    for (int j = t; j < nb; j += 256) {
        uint2 rec;
        if (j < STAGE_CAP) rec = stage[j];
        else {
            int lo = 0, hi = PREB - 1;
            while (lo < hi) { int mid = (lo + hi + 1) >> 1; if (rpos[mid] <= j) lo = mid; else hi = mid - 1; }
            rec = etmp[(size_t)lo * EB + lloff[lo] + (j - rpos[lo])];
        }
        int rl = (rec.x >> 16) & 63;
        int dst = atomicAdd(&rcur[rl], 1);
        if (dst < BUKCAP) edata[(size_t)base + dst] = rec;
    }
}

// ---------------------------------------------------------------------------
// Fused softmax + SpMM: one wave per row; f16 dot2 gather pipeline.
// rowinfo = {beg(abs), deg}. Writes aggregated row as bf16.
// ---------------------------------------------------------------------------
__global__ void attn_kernel(const uint2* __restrict__ rowinfo,
                            const uint2* __restrict__ edata,
                            const unsigned* __restrict__ wxi,
                            ushort_t* __restrict__ aacc) {
    int wid = blockIdx.x * 4 + (threadIdx.x >> 6);
    if (wid >= N_NODES) return;
    int lane = threadIdx.x & 63;
    uint2 ri = rowinfo[wid];
    int beg = (int)ri.x;
    int deg = (int)ri.y;
    float a = 0.f;

    if (deg > 0 && deg <= 64) {
        bool valid = lane < deg;
        uint2 ed = edata[valid ? beg + lane : beg];
        unsigned c = ed.x & 0xFFFFu;
        float sc0, sc1;
        unpack_h2(ed.y, sc0, sc1);
        if (!valid) { sc0 = NEG_INF; sc1 = NEG_INF; }
        float m0 = sc0, m1 = sc1;
#pragma unroll
        for (int off = 32; off > 0; off >>= 1) {
            m0 = fmaxf(m0, __shfl_xor(m0, off));
            m1 = fmaxf(m1, __shfl_xor(m1, off));
        }
        float e0 = valid ? __expf(sc0 - m0) : 0.f;
        float e1 = valid ? __expf(sc1 - m1) : 0.f;
        float l0 = e0, l1 = e1;
#pragma unroll
        for (int off = 32; off > 0; off >>= 1) {
            l0 += __shfl_xor(l0, off);
            l1 += __shfl_xor(l1, off);
        }
        unsigned pp = pack_h2(e0 / l0, e1 / l1);   // {p0,p1} f16 pair
        float acc8[8] = {};
        int i = 0;
        for (; i + 8 <= deg; i += 8) {
            unsigned cc[8], vv[8];
#pragma unroll
            for (int j = 0; j < 8; ++j) cc[j] = rl_u(c, i + j);
#pragma unroll
            for (int j = 0; j < 8; ++j) vv[j] = wxi[(size_t)cc[j] * OUT_DIM + lane];
#pragma unroll
            for (int j = 0; j < 8; ++j)
                acc8[j] = dot2u(vv[j], rl_u(pp, i + j), acc8[j]);
        }
        for (; i < deg; ++i) {
            unsigned ci = rl_u(c, i);
            unsigned v = wxi[(size_t)ci * OUT_DIM + lane];
            acc8[0] = dot2u(v, rl_u(pp, i), acc8[0]);
        }
        a = ((acc8[0] + acc8[1]) + (acc8[2] + acc8[3]))
          + ((acc8[4] + acc8[5]) + (acc8[6] + acc8[7]));
    } else if (deg > 64) {
        int end = beg + deg;
        float m0 = NEG_INF, l0 = 0.f, m1 = NEG_INF, l1 = 0.f;
        for (int base = beg; base < end; base += 64) {
            int pos = base + lane;
            bool valid = pos < end;
            uint2 ed = edata[valid ? pos : beg];
            float sc0, sc1;
            unpack_h2(ed.y, sc0, sc1);
            if (!valid) { sc0 = NEG_INF; sc1 = NEG_INF; }
            float cm0 = sc0, cm1 = sc1;
#pragma unroll
            for (int off = 32; off > 0; off >>= 1) {
                cm0 = fmaxf(cm0, __shfl_xor(cm0, off));
                cm1 = fmaxf(cm1, __shfl_xor(cm1, off));
            }
            float mn0 = fmaxf(m0, cm0), mn1 = fmaxf(m1, cm1);
            float e0 = valid ? __expf(sc0 - mn0) : 0.f;
            float e1 = valid ? __expf(sc1 - mn1) : 0.f;
#pragma unroll
            for (int off = 32; off > 0; off >>= 1) {
                e0 += __shfl_xor(e0, off);
                e1 += __shfl_xor(e1, off);
            }
            l0 = l0 * __expf(m0 - mn0) + e0;
            l1 = l1 * __expf(m1 - mn1) + e1;
            m0 = mn0; m1 = mn1;
        }
        float inv0 = 1.f / l0, inv1 = 1.f / l1;
        for (int base = beg; base < end; base += 64) {
            int pos = base + lane;
            bool valid = pos < end;
            uint2 ed = edata[valid ? pos : beg];
            unsigned c = ed.x & 0xFFFFu;
            float sc0, sc1;
            unpack_h2(ed.y, sc0, sc1);
            float p0 = valid ? __expf(sc0 - m0) * inv0 : 0.f;
            float p1 = valid ? __expf(sc1 - m1) * inv1 : 0.f;
            unsigned pp = pack_h2(p0, p1);
            int cnt = min(64, end - base);
            for (int i = 0; i < cnt; ++i) {
                unsigned ci = rl_u(c, i);
                unsigned v = wxi[(size_t)ci * OUT_DIM + lane];
                a = dot2u(v, rl_u(pp, i), a);
            }
        }
    }
    aacc[(size_t)wid * OUT_DIM + lane] = (ushort_t)f2bf(a);
}

// ---------------------------------------------------------------------------
// Residual MFMA: out = elu(xresh + aacc @ Wres[128:]); 16 rows per wave.
// ---------------------------------------------------------------------------
__global__ __launch_bounds__(256) void resid_kernel(
        const ushort_t* __restrict__ aacc,
        const ushort_t* __restrict__ xresh,
        const ushort_t* __restrict__ Wpack,
        float* __restrict__ out) {
    int wave = threadIdx.x >> 6;
    int lane = threadIdx.x & 63;
    int lr = lane & 15;
    int lg = lane >> 4;
    int row0 = blockIdx.x * 64 + wave * 16;
    int arow = row0 + lr;
    if (arow >= N_NODES) arow = N_NODES - 1;
    const ushort_t* ap = aacc + (size_t)arow * OUT_DIM;
    short8 af[2];
#pragma unroll
    for (int kc = 0; kc < 2; ++kc)
        af[kc] = *(const short8*)(ap + kc * 32 + lg * 8);
    f32x4 acc4[4] = {};
#pragma unroll
    for (int kc = 0; kc < 2; ++kc) {
#pragma unroll
        for (int ct = 0; ct < 4; ++ct) {
            short8 bfrag = *(const short8*)(
                Wpack + (size_t)((48 + ct * 2 + kc) << 9) + lane * 8);
            acc4[ct] = __builtin_amdgcn_mfma_f32_16x16x32_bf16(
                af[kc], bfrag, acc4[ct], 0, 0, 0);
        }
    }
#pragma unroll
    for (int r = 0; r < 4; ++r) {
        int gr = row0 + lg * 4 + r;
        if (gr < N_NODES) {
#pragma unroll
            for (int ct = 0; ct < 4; ++ct) {
                float v = acc4[ct][r] + bf2f(xresh[(size_t)gr * OUT_DIM + ct * 16 + lr]);
                out[(size_t)gr * OUT_DIM + ct * 16 + lr] = (v > 0.f) ? v : expm1f(v);
            }
        }
    }
}

extern "C" void kernel_launch(void* const* d_in, const int* in_sizes, int n_in,
                              void* d_out, int out_size, void* d_ws, size_t ws_size,
                              hipStream_t stream) {
    const float* x       = (const float*)d_in[0];
    const float* support = (const float*)d_in[1];
    const float* atten   = (const float*)d_in[2];
    const float* Wt      = (const float*)d_in[3];
    const float* wl      = (const float*)d_in[4];
    const float* wr      = (const float*)d_in[5];
    const float* Wres    = (const float*)d_in[6];
    const int*   rows    = (const int*)d_in[7];
    const int*   cols    = (const int*)d_in[8];
    float* out = (float*)d_out;

    // workspace layout (16B-aligned sections)
    unsigned* wxi    = (unsigned*)d_ws;                                // N*64
    ushort_t* xresh  = (ushort_t*)(wxi + (size_t)N_NODES * OUT_DIM);   // N*64 bf16
    float* al        = (float*)(xresh + (size_t)N_NODES * OUT_DIM);    // N*6
    float* ar        = al + (size_t)N_NODES * 6;                       // N*6
    uint2* etmp      = (uint2*)(ar + (size_t)N_NODES * 6);             // E * 8B
    uint2* edata     = etmp + (size_t)N_EDGES;                         // NBUK*BUKCAP * 8B
    uint2* rowinfo   = edata + (size_t)NBUK * BUKCAP;                  // N
    uint2* cl        = rowinfo + N_NODES + 4;                          // PREB*NBUKP
    ushort_t* Wpack  = (ushort_t*)(cl + (size_t)PREB * NBUKP);         // NFRAG*512
    ushort_t* aacc   = (ushort_t*)etmp;   // etmp dead after sortb

    wpack_kernel<<<(NFRAG * 512 + 255) / 256, 256, 0, stream>>>(Wt, Wres, Wpack);
    gemm_kernel<<<GBLK, 256, 0, stream>>>(x, Wpack, wl, wr, wxi, xresh, al, ar);
    score_sort_kernel<<<PREB, 256, 0, stream>>>(
        rows, cols, atten, support, al, ar, etmp, cl);
    sortb_kernel<<<NBUK, 256, 0, stream>>>(cl, etmp, edata, rowinfo);
    attn_kernel<<<(N_NODES + 3) / 4, 256, 0, stream>>>(
        rowinfo, edata, wxi, aacc);
    resid_kernel<<<GBLK, 256, 0, stream>>>(aacc, xresh, Wpack, out);
}